// Round 1
// baseline (825.495 us; speedup 1.0000x reference)
//
#include <hip/hip_runtime.h>

// CrossAttentionDecoder: B=1024, n_tok=16, n_lat=128, d=512, h=8, dh=64
// Pipeline: castW -> Q/K/V proj (bf16 MFMA GEMM) -> fused attention -> O proj.

typedef __bf16 bf16;
typedef __attribute__((ext_vector_type(8))) __bf16 bf16x8;
typedef __attribute__((ext_vector_type(4))) __bf16 bf16x4;
typedef __attribute__((ext_vector_type(4))) float  float4v;

#define MFMA16(a, b, c) __builtin_amdgcn_mfma_f32_16x16x32_bf16((a), (b), (c), 0, 0, 0)

// ---------------------------------------------------------------------------
// Cast one 512x512 fp32 weight matrix to bf16. grid 256 x 256 threads x 4 elems.
__global__ __launch_bounds__(256) void cast_w(const float* __restrict__ src,
                                              bf16* __restrict__ dst) {
    int i = (blockIdx.x * 256 + threadIdx.x) * 4;
    float4v f = *(const float4v*)(src + i);
    bf16x4 o = {(bf16)f.x, (bf16)f.y, (bf16)f.z, (bf16)f.w};
    *(bf16x4*)(dst + i) = o;
}

// ---------------------------------------------------------------------------
// C[M x 512] = A[M x 512] @ W[512 x 512]^T   (W row-major, K contiguous: BT form)
// Tile: BM=BN=128, BK=32. 256 threads = 4 waves, each wave owns a 64x64 quadrant
// (4x4 tiles of 16x16x32 bf16 MFMA).
// AFP32: A is fp32 (converted to bf16 during LDS staging), else A is bf16.
// FOUT : write fp32 + bias[col], else write bf16.
template <bool AFP32, bool FOUT>
__global__ __launch_bounds__(256) void gemm_bt(const void* __restrict__ Ap,
                                               const bf16* __restrict__ W,
                                               void* __restrict__ Cp,
                                               const float* __restrict__ bias) {
    __shared__ bf16 Asl[128 * 32];
    __shared__ bf16 Bsl[128 * 32];

    const int tid  = threadIdx.x;
    const int n0   = blockIdx.x * 128;   // output-col tile (x fastest: A-tile L2 reuse)
    const int m0   = blockIdx.y * 128;

    const int wave = tid >> 6;
    const int lane = tid & 63;
    const int mi   = lane & 15;
    const int quad = lane >> 4;
    const int qrow = (wave >> 1) * 64;
    const int qcol = (wave & 1) * 64;

    const int sr = tid >> 1;             // staging row 0..127
    const int sc = (tid & 1) * 16;       // staging col 0 or 16

    float4v acc[4][4] = {};

    for (int kt = 0; kt < 16; ++kt) {
        const int k0 = kt * 32;
        // ---- stage A tile (128 x 32) ----
        if (AFP32) {
            const float* A = (const float*)Ap + (m0 + sr) * 512 + k0 + sc;
            float4v f0 = ((const float4v*)A)[0];
            float4v f1 = ((const float4v*)A)[1];
            float4v f2 = ((const float4v*)A)[2];
            float4v f3 = ((const float4v*)A)[3];
            bf16* d = &Asl[sr * 32 + sc];
            ((bf16x4*)d)[0] = bf16x4{(bf16)f0.x, (bf16)f0.y, (bf16)f0.z, (bf16)f0.w};
            ((bf16x4*)d)[1] = bf16x4{(bf16)f1.x, (bf16)f1.y, (bf16)f1.z, (bf16)f1.w};
            ((bf16x4*)d)[2] = bf16x4{(bf16)f2.x, (bf16)f2.y, (bf16)f2.z, (bf16)f2.w};
            ((bf16x4*)d)[3] = bf16x4{(bf16)f3.x, (bf16)f3.y, (bf16)f3.z, (bf16)f3.w};
        } else {
            const bf16* A = (const bf16*)Ap + (m0 + sr) * 512 + k0 + sc;
            bf16* d = &Asl[sr * 32 + sc];
            ((bf16x8*)d)[0] = ((const bf16x8*)A)[0];
            ((bf16x8*)d)[1] = ((const bf16x8*)A)[1];
        }
        // ---- stage W tile (128 x 32), always bf16 ----
        {
            const bf16* Wp = W + (n0 + sr) * 512 + k0 + sc;
            bf16* d = &Bsl[sr * 32 + sc];
            ((bf16x8*)d)[0] = ((const bf16x8*)Wp)[0];
            ((bf16x8*)d)[1] = ((const bf16x8*)Wp)[1];
        }
        __syncthreads();

        bf16x8 af[4], bfr[4];
#pragma unroll
        for (int i = 0; i < 4; ++i)
            af[i] = *(const bf16x8*)&Asl[(qrow + i * 16 + mi) * 32 + quad * 8];
#pragma unroll
        for (int j = 0; j < 4; ++j)
            bfr[j] = *(const bf16x8*)&Bsl[(qcol + j * 16 + mi) * 32 + quad * 8];
#pragma unroll
        for (int i = 0; i < 4; ++i)
#pragma unroll
            for (int j = 0; j < 4; ++j)
                acc[i][j] = MFMA16(af[i], bfr[j], acc[i][j]);
        __syncthreads();
    }

    // ---- epilogue: D[row=quad*4+r][col=mi] per 16x16 tile ----
#pragma unroll
    for (int i = 0; i < 4; ++i) {
#pragma unroll
        for (int j = 0; j < 4; ++j) {
            const int row = m0 + qrow + i * 16 + quad * 4;
            const int col = n0 + qcol + j * 16 + mi;
#pragma unroll
            for (int r = 0; r < 4; ++r) {
                float v = acc[i][j][r];
                if (FOUT)
                    ((float*)Cp)[(row + r) * 512 + col] = v + bias[col];
                else
                    ((bf16*)Cp)[(row + r) * 512 + col] = (bf16)v;
            }
        }
    }
}

// ---------------------------------------------------------------------------
// Attention: one wave per (b, h). Q:16x64, K/V:128x64 slices (stride 512).
// scores = Q K^T * dh^-0.5, causal-latent mask (j <= b%128), softmax over j,
// out = P V. Q/K fragments straight from global; P and V^T staged in LDS.
__global__ __launch_bounds__(64) void attn_kernel(const bf16* __restrict__ Q,
                                                  const bf16* __restrict__ K,
                                                  const bf16* __restrict__ V,
                                                  bf16* __restrict__ O) {
    __shared__ bf16 Plds[16 * 128];   // P[tok][lat]
    __shared__ bf16 Vt[64 * 128];     // V^T[d][lat]

    const int bh   = blockIdx.x;
    const int b    = bh >> 3;
    const int h    = bh & 7;
    const int rowb = b & 127;         // allowed latents: j <= rowb
    const int lane = threadIdx.x;
    const int mi   = lane & 15;
    const int quad = lane >> 4;

    // Q fragments: A[m=tok=mi][k=dh], two K=32 steps
    const bf16* qbase = Q + (b * 16 + mi) * 512 + h * 64 + quad * 8;
    bf16x8 aq0 = *(const bf16x8*)(qbase);
    bf16x8 aq1 = *(const bf16x8*)(qbase + 32);

    // scores: 8 tiles of 16 latents; B[k=dh][n=lat] read as K rows (BT form)
    float4v sc[8];
    const bf16* kbase = K + (b * 128 + mi) * 512 + h * 64 + quad * 8;
#pragma unroll
    for (int jt = 0; jt < 8; ++jt) {
        const bf16* kb = kbase + jt * 16 * 512;
        bf16x8 bk0 = *(const bf16x8*)(kb);
        bf16x8 bk1 = *(const bf16x8*)(kb + 32);
        float4v a = {};
        a = MFMA16(aq0, bk0, a);
        a = MFMA16(aq1, bk1, a);
        sc[jt] = a;
    }

    // mask + scale (col = latent = jt*16 + mi, same for all 4 regs)
#pragma unroll
    for (int jt = 0; jt < 8; ++jt) {
        const bool masked = (jt * 16 + mi) > rowb;
#pragma unroll
        for (int r = 0; r < 4; ++r)
            sc[jt][r] = masked ? -1e30f : sc[jt][r] * 0.125f;
    }

    // softmax per token row (row = quad*4 + r); reduce across 16 lanes (mi)
#pragma unroll
    for (int r = 0; r < 4; ++r) {
        float mx = sc[0][r];
#pragma unroll
        for (int jt = 1; jt < 8; ++jt) mx = fmaxf(mx, sc[jt][r]);
#pragma unroll
        for (int off = 1; off < 16; off <<= 1) mx = fmaxf(mx, __shfl_xor(mx, off, 64));
        float s = 0.f;
#pragma unroll
        for (int jt = 0; jt < 8; ++jt) {
            float p = __expf(sc[jt][r] - mx);   // masked -> exp(-huge) = 0
            sc[jt][r] = p;
            s += p;
        }
#pragma unroll
        for (int off = 1; off < 16; off <<= 1) s += __shfl_xor(s, off, 64);
        const float inv = 1.f / s;
#pragma unroll
        for (int jt = 0; jt < 8; ++jt)
            Plds[(quad * 4 + r) * 128 + jt * 16 + mi] = (bf16)(sc[jt][r] * inv);
    }

    // stage V^T: V[lat][d] -> Vt[d][lat]
    const int vr = lane >> 3;        // 0..7
    const int vc = lane & 7;         // 0..7 (d-octet)
#pragma unroll
    for (int p = 0; p < 16; ++p) {
        const int lat = p * 8 + vr;
        bf16x8 v8 = *(const bf16x8*)(V + (b * 128 + lat) * 512 + h * 64 + vc * 8);
#pragma unroll
        for (int e = 0; e < 8; ++e) Vt[(vc * 8 + e) * 128 + lat] = v8[e];
    }
    __syncthreads();

    // out = P @ V : A[m=tok][k=lat] from Plds, B[k=lat][n=d] from Vt (BT form)
    float4v ao[4] = {};
#pragma unroll
    for (int ks = 0; ks < 4; ++ks) {
        bf16x8 ap = *(const bf16x8*)&Plds[mi * 128 + ks * 32 + quad * 8];
#pragma unroll
        for (int jt = 0; jt < 4; ++jt) {
            bf16x8 bv = *(const bf16x8*)&Vt[(jt * 16 + mi) * 128 + ks * 32 + quad * 8];
            ao[jt] = MFMA16(ap, bv, ao[jt]);
        }
    }

    // write merged-head output (B*16, 512) bf16
#pragma unroll
    for (int jt = 0; jt < 4; ++jt)
#pragma unroll
        for (int r = 0; r < 4; ++r)
            O[(b * 16 + quad * 4 + r) * 512 + h * 64 + jt * 16 + mi] = (bf16)ao[jt][r];
}

// ---------------------------------------------------------------------------
extern "C" void kernel_launch(void* const* d_in, const int* in_sizes, int n_in,
                              void* d_out, int out_size, void* d_ws, size_t ws_size,
                              hipStream_t stream) {
    const float* x  = (const float*)d_in[0];   // (1024*16, 512) viewed flat
    const float* l  = (const float*)d_in[1];   // (1024*128, 512)
    const float* Wq = (const float*)d_in[2];
    const float* Wk = (const float*)d_in[3];
    const float* Wv = (const float*)d_in[4];
    const float* Wo = (const float*)d_in[5];
    const float* bo = (const float*)d_in[6];
    // d_in[7] = num_heads (8), hard-coded.

    char* ws = (char*)d_ws;
    const size_t WSZ = 512 * 512 * 2;            // one bf16 weight: 512 KiB
    bf16* Wq_b = (bf16*)(ws + 0 * WSZ);
    bf16* Wk_b = (bf16*)(ws + 1 * WSZ);
    bf16* Wv_b = (bf16*)(ws + 2 * WSZ);
    bf16* Wo_b = (bf16*)(ws + 3 * WSZ);
    size_t off = 4 * WSZ;
    bf16* Qb  = (bf16*)(ws + off); off += (size_t)16384 * 512 * 2;   // 16 MiB
    bf16* Kb  = (bf16*)(ws + off); off += (size_t)131072 * 512 * 2;  // 128 MiB
    bf16* Vb  = (bf16*)(ws + off); off += (size_t)131072 * 512 * 2;  // 128 MiB
    bf16* AOb = (bf16*)(ws + off);                                   // 16 MiB

    cast_w<<<256, 256, 0, stream>>>(Wq, Wq_b);
    cast_w<<<256, 256, 0, stream>>>(Wk, Wk_b);
    cast_w<<<256, 256, 0, stream>>>(Wv, Wv_b);
    cast_w<<<256, 256, 0, stream>>>(Wo, Wo_b);

    gemm_bt<true, false><<<dim3(4, 128),  256, 0, stream>>>(x, Wq_b, Qb, nullptr);
    gemm_bt<true, false><<<dim3(4, 1024), 256, 0, stream>>>(l, Wk_b, Kb, nullptr);
    gemm_bt<true, false><<<dim3(4, 1024), 256, 0, stream>>>(l, Wv_b, Vb, nullptr);

    attn_kernel<<<8192, 64, 0, stream>>>(Qb, Kb, Vb, AOb);

    gemm_bt<false, true><<<dim3(4, 128), 256, 0, stream>>>(AOb, Wo_b, d_out, bo);
}

// Round 2
// 730.342 us; speedup vs baseline: 1.1303x; 1.1303x over previous
//
#include <hip/hip_runtime.h>

// CrossAttentionDecoder: B=1024, n_tok=16, n_lat=128, d=512, h=8, dh=64
// Pipeline: cast(w,x,l)->bf16 -> Q proj -> fused KV proj -> masked attn -> O proj.

typedef __bf16 bf16;
typedef __attribute__((ext_vector_type(8))) __bf16 bf16x8;
typedef __attribute__((ext_vector_type(4))) __bf16 bf16x4;
typedef __attribute__((ext_vector_type(4))) float  float4v;

#define MFMA16(a, b, c) __builtin_amdgcn_mfma_f32_16x16x32_bf16((a), (b), (c), 0, 0, 0)

// global -> LDS direct 16B copy: per-lane global addr, wave-uniform LDS base,
// lane i lands at ldsbase + i*16 (m97/m104 semantics).
__device__ __forceinline__ void gl2lds16(const bf16* g, bf16* l) {
    __builtin_amdgcn_global_load_lds(
        (const __attribute__((address_space(1))) void*)g,
        (__attribute__((address_space(3))) void*)l, 16, 0, 0);
}

// ---------------------------------------------------------------------------
// Generic fp32 -> bf16 cast, 4 elems/thread, grid-stride.
__global__ __launch_bounds__(256) void cast_f32_bf16(const float* __restrict__ src,
                                                     bf16* __restrict__ dst, int n4) {
    const int stride = gridDim.x * 256;
    for (int i = blockIdx.x * 256 + threadIdx.x; i < n4; i += stride) {
        float4v f = ((const float4v*)src)[i];
        ((bf16x4*)dst)[i] = bf16x4{(bf16)f.x, (bf16)f.y, (bf16)f.z, (bf16)f.w};
    }
}

// All four 512x512 weights in one launch. Wk,Wv go adjacent (Wkv = [Wk;Wv]).
__global__ __launch_bounds__(256) void cast_weights(const float* __restrict__ Wq,
                                                    const float* __restrict__ Wk,
                                                    const float* __restrict__ Wv,
                                                    const float* __restrict__ Wo,
                                                    bf16* __restrict__ Wq_b,
                                                    bf16* __restrict__ Wkv_b,
                                                    bf16* __restrict__ Wo_b) {
    const int i = blockIdx.x * 256 + threadIdx.x;  // 0 .. 4*65536-1 (float4 units)
    const int w = i >> 16;
    const int j = i & 65535;
    const float* src = (w == 0) ? Wq : (w == 1) ? Wk : (w == 2) ? Wv : Wo;
    bf16x4* dst = (w == 0) ? (bf16x4*)Wq_b
                : (w == 1) ? (bf16x4*)Wkv_b
                : (w == 2) ? ((bf16x4*)Wkv_b) + 65536
                           : (bf16x4*)Wo_b;
    float4v f = ((const float4v*)src)[j];
    dst[j] = bf16x4{(bf16)f.x, (bf16)f.y, (bf16)f.z, (bf16)f.w};
}

// ---------------------------------------------------------------------------
// C[M x N] = A[M x 512] @ W[N x 512]^T, A/W bf16, K=512 (16 steps of BK=32).
// BM=BN=128, 256 thr = 4 waves, wave owns 64x64 (4x4 MFMA 16x16x32 tiles).
// Staging via global_load_lds width 16. FOUT: fp32 + bias[col] out, else bf16.
template <bool FOUT>
__global__ __launch_bounds__(256) void gemm_bt(const bf16* __restrict__ A,
                                               const bf16* __restrict__ W,
                                               void* __restrict__ Cp,
                                               const float* __restrict__ bias,
                                               int ldC) {
    __shared__ alignas(16) bf16 Asl[128 * 32];
    __shared__ alignas(16) bf16 Bsl[128 * 32];

    const int tid  = threadIdx.x;
    const int n0   = blockIdx.x * 128;   // x fastest: A-tile shared across n-tiles
    const int m0   = blockIdx.y * 128;

    const int wave = tid >> 6;
    const int lane = tid & 63;
    const int mi   = lane & 15;
    const int quad = lane >> 4;
    const int qrow = (wave >> 1) * 64;
    const int qcol = (wave & 1) * 64;

    // staging: LDS linear byte = wave*1024 + r*4096 + lane*16
    //   row = wave*16 + r*64 + lane/4 ; col elems = (lane&3)*8
    const int srow = wave * 16 + (lane >> 2);
    const int scol = (lane & 3) * 8;

    float4v acc[4][4] = {};

    for (int kt = 0; kt < 16; ++kt) {
        const int k0 = kt * 32;
#pragma unroll
        for (int r = 0; r < 2; ++r) {
            gl2lds16(A + (size_t)(m0 + srow + r * 64) * 512 + k0 + scol,
                     &Asl[wave * 512 + r * 2048]);
            gl2lds16(W + (size_t)(n0 + srow + r * 64) * 512 + k0 + scol,
                     &Bsl[wave * 512 + r * 2048]);
        }
        __syncthreads();

        bf16x8 af[4], bfr[4];
#pragma unroll
        for (int i = 0; i < 4; ++i)
            af[i] = *(const bf16x8*)&Asl[(qrow + i * 16 + mi) * 32 + quad * 8];
#pragma unroll
        for (int j = 0; j < 4; ++j)
            bfr[j] = *(const bf16x8*)&Bsl[(qcol + j * 16 + mi) * 32 + quad * 8];
#pragma unroll
        for (int i = 0; i < 4; ++i)
#pragma unroll
            for (int j = 0; j < 4; ++j)
                acc[i][j] = MFMA16(af[i], bfr[j], acc[i][j]);
        __syncthreads();
    }

    // epilogue: D[row = quad*4 + r][col = mi] per 16x16 tile
#pragma unroll
    for (int i = 0; i < 4; ++i) {
#pragma unroll
        for (int j = 0; j < 4; ++j) {
            const int row = m0 + qrow + i * 16 + quad * 4;
            const int col = n0 + qcol + j * 16 + mi;
#pragma unroll
            for (int r = 0; r < 4; ++r) {
                float v = acc[i][j][r];
                if (FOUT)
                    ((float*)Cp)[(size_t)(row + r) * ldC + col] = v + bias[col];
                else
                    ((bf16*)Cp)[(size_t)(row + r) * ldC + col] = (bf16)v;
            }
        }
    }
}

// ---------------------------------------------------------------------------
// Attention: one wave per (b, h). KV row-major (131072, 1024): K cols 0..511,
// V cols 512..1023. Mask-aware: only ntiles = rowb/16+1 latent tiles computed.
// LDS: only padded P tile (16 x 136 bf16) -> high occupancy.
__global__ __launch_bounds__(64) void attn_kernel(const bf16* __restrict__ Q,
                                                  const bf16* __restrict__ KV,
                                                  bf16* __restrict__ O) {
    __shared__ alignas(16) bf16 Plds[16 * 136];   // +8 pad breaks 16-way conflicts

    const int bh     = blockIdx.x;
    const int b      = bh >> 3;
    const int h      = bh & 7;
    const int rowb   = b & 127;                   // allowed latents: j <= rowb
    const int ntiles = (rowb >> 4) + 1;           // active 16-latent tiles (1..8)
    const int nkt    = (ntiles + 1) >> 1;         // active 32-latent PV k-steps
    const int lane   = threadIdx.x;
    const int mi     = lane & 15;
    const int quad   = lane >> 4;

    // Q fragments: A[m=tok=mi][k=dh=quad*8+j], two K=32 chunks
    const bf16* qbase = Q + (size_t)(b * 16 + mi) * 512 + h * 64 + quad * 8;
    const bf16x8 aq0 = *(const bf16x8*)(qbase);
    const bf16x8 aq1 = *(const bf16x8*)(qbase + 32);

    // scores: B[k=dh][n=lat] from K rows (BT form)
    float4v sc[8];
    const bf16* kbase = KV + (size_t)(b * 128 + mi) * 1024 + h * 64 + quad * 8;
#pragma unroll
    for (int jt = 0; jt < 8; ++jt) {
        if (jt < ntiles) {
            const bf16* kb = kbase + (size_t)jt * 16 * 1024;
            bf16x8 bk0 = *(const bf16x8*)(kb);
            bf16x8 bk1 = *(const bf16x8*)(kb + 32);
            float4v a = {};
            a = MFMA16(aq0, bk0, a);
            a = MFMA16(aq1, bk1, a);
            sc[jt] = a;
        }
    }

    // mask boundary tile + scale  (col = jt*16 + mi)
#pragma unroll
    for (int jt = 0; jt < 8; ++jt) {
        if (jt < ntiles) {
            const bool masked = (jt * 16 + mi) > rowb;
#pragma unroll
            for (int r = 0; r < 4; ++r)
                sc[jt][r] = masked ? -1e30f : sc[jt][r] * 0.125f;
        }
    }

    // softmax per token row (row = quad*4+r), reduce across the 16 mi lanes
#pragma unroll
    for (int r = 0; r < 4; ++r) {
        float mx = sc[0][r];
#pragma unroll
        for (int jt = 1; jt < 8; ++jt)
            if (jt < ntiles) mx = fmaxf(mx, sc[jt][r]);
#pragma unroll
        for (int off = 1; off < 16; off <<= 1) mx = fmaxf(mx, __shfl_xor(mx, off, 64));
        float s = 0.f;
#pragma unroll
        for (int jt = 0; jt < 8; ++jt) {
            if (jt < ntiles) {
                float p = __expf(sc[jt][r] - mx);
                sc[jt][r] = p;
                s += p;
            }
        }
#pragma unroll
        for (int off = 1; off < 16; off <<= 1) s += __shfl_xor(s, off, 64);
        const float inv = 1.f / s;
        // store active tiles; zero-fill ragged upper half of last 32-block
#pragma unroll
        for (int jt = 0; jt < 8; ++jt) {
            if (jt < 2 * nkt) {
                float p = (jt < ntiles) ? sc[jt][r] * inv : 0.f;
                Plds[(quad * 4 + r) * 136 + jt * 16 + mi] = (bf16)p;
            }
        }
    }
    __syncthreads();   // single-wave block: compiles to a waitcnt

    // out = P @ V. A[m=tok][k=lat] from Plds; B[k=lat][n=d]: lane mi = d col,
    // k = quad*8+j -> 8 scalar V loads per fragment (L2/LLC-resident).
    float4v ao[4] = {};
#pragma unroll
    for (int ks = 0; ks < 4; ++ks) {
        if (ks < nkt) {
            bf16x8 ap = *(const bf16x8*)&Plds[mi * 136 + ks * 32 + quad * 8];
            const bf16* vbase = KV + (size_t)(b * 128 + ks * 32 + quad * 8) * 1024
                               + 512 + h * 64;
#pragma unroll
            for (int jt = 0; jt < 4; ++jt) {
                bf16x8 bv;
#pragma unroll
                for (int j = 0; j < 8; ++j)
                    bv[j] = vbase[(size_t)j * 1024 + jt * 16 + mi];
                ao[jt] = MFMA16(ap, bv, ao[jt]);
            }
        }
    }

    // write merged-head output (16384, 512) bf16
#pragma unroll
    for (int jt = 0; jt < 4; ++jt)
#pragma unroll
        for (int r = 0; r < 4; ++r)
            O[(size_t)(b * 16 + quad * 4 + r) * 512 + h * 64 + jt * 16 + mi] =
                (bf16)ao[jt][r];
}

// ---------------------------------------------------------------------------
extern "C" void kernel_launch(void* const* d_in, const int* in_sizes, int n_in,
                              void* d_out, int out_size, void* d_ws, size_t ws_size,
                              hipStream_t stream) {
    const float* x  = (const float*)d_in[0];   // (16384, 512)
    const float* l  = (const float*)d_in[1];   // (131072, 512)
    const float* Wq = (const float*)d_in[2];
    const float* Wk = (const float*)d_in[3];
    const float* Wv = (const float*)d_in[4];
    const float* Wo = (const float*)d_in[5];
    const float* bo = (const float*)d_in[6];
    // d_in[7] = num_heads (8), hard-coded.

    char* ws = (char*)d_ws;
    size_t off = 0;
    bf16* Wq_b  = (bf16*)(ws + off); off += (size_t)512 * 512 * 2;
    bf16* Wo_b  = (bf16*)(ws + off); off += (size_t)512 * 512 * 2;
    bf16* Wkv_b = (bf16*)(ws + off); off += (size_t)1024 * 512 * 2;   // [Wk;Wv]
    bf16* xb    = (bf16*)(ws + off); off += (size_t)16384 * 512 * 2;
    bf16* lb    = (bf16*)(ws + off); off += (size_t)131072 * 512 * 2;
    bf16* Qb    = (bf16*)(ws + off); off += (size_t)16384 * 512 * 2;
    bf16* KVb   = (bf16*)(ws + off); off += (size_t)131072 * 1024 * 2;
    bf16* AOb   = (bf16*)(ws + off);

    cast_weights<<<1024, 256, 0, stream>>>(Wq, Wk, Wv, Wo, Wq_b, Wkv_b, Wo_b);
    cast_f32_bf16<<<2048, 256, 0, stream>>>(x, xb, 16384 * 512 / 4);
    cast_f32_bf16<<<8192, 256, 0, stream>>>(l, lb, 131072 * 512 / 4);

    gemm_bt<false><<<dim3(4, 128),  256, 0, stream>>>(xb, Wq_b,  Qb,  nullptr, 512);
    gemm_bt<false><<<dim3(8, 1024), 256, 0, stream>>>(lb, Wkv_b, KVb, nullptr, 1024);

    attn_kernel<<<8192, 64, 0, stream>>>(Qb, KVb, AOb);

    gemm_bt<true><<<dim3(4, 128), 256, 0, stream>>>(AOb, Wo_b, d_out, bo, 512);
}

// Round 3
// 714.589 us; speedup vs baseline: 1.1552x; 1.0220x over previous
//
#include <hip/hip_runtime.h>

// CrossAttentionDecoder: B=1024, n_tok=16, n_lat=128, d=512, h=8, dh=64
// cast(w,x,l)->bf16 -> Q proj -> fused KV proj (K row-major, V transposed)
// -> masked attn -> O proj.  All GEMM blocks XCD-swizzled for L2 A-reuse.

typedef __bf16 bf16;
typedef __attribute__((ext_vector_type(8))) __bf16 bf16x8;
typedef __attribute__((ext_vector_type(4))) __bf16 bf16x4;
typedef __attribute__((ext_vector_type(4))) float  float4v;

#define MFMA16(a, b, c) __builtin_amdgcn_mfma_f32_16x16x32_bf16((a), (b), (c), 0, 0, 0)

// global -> LDS direct 16B copy: per-lane global addr, wave-uniform LDS base,
// lane i lands at ldsbase + i*16 (m97/m104 semantics).
__device__ __forceinline__ void gl2lds16(const bf16* g, bf16* l) {
    __builtin_amdgcn_global_load_lds(
        (const __attribute__((address_space(1))) void*)g,
        (__attribute__((address_space(3))) void*)l, 16, 0, 0);
}

// ---------------------------------------------------------------------------
__global__ __launch_bounds__(256) void cast_f32_bf16(const float* __restrict__ src,
                                                     bf16* __restrict__ dst, int n4) {
    const int stride = gridDim.x * 256;
    for (int i = blockIdx.x * 256 + threadIdx.x; i < n4; i += stride) {
        float4v f = ((const float4v*)src)[i];
        ((bf16x4*)dst)[i] = bf16x4{(bf16)f.x, (bf16)f.y, (bf16)f.z, (bf16)f.w};
    }
}

__global__ __launch_bounds__(256) void cast_weights(const float* __restrict__ Wq,
                                                    const float* __restrict__ Wk,
                                                    const float* __restrict__ Wv,
                                                    const float* __restrict__ Wo,
                                                    bf16* __restrict__ Wq_b,
                                                    bf16* __restrict__ Wkv_b,
                                                    bf16* __restrict__ Wo_b) {
    const int i = blockIdx.x * 256 + threadIdx.x;  // float4 units
    const int w = i >> 16;
    const int j = i & 65535;
    const float* src = (w == 0) ? Wq : (w == 1) ? Wk : (w == 2) ? Wv : Wo;
    bf16x4* dst = (w == 0) ? (bf16x4*)Wq_b
                : (w == 1) ? (bf16x4*)Wkv_b
                : (w == 2) ? ((bf16x4*)Wkv_b) + 65536
                           : (bf16x4*)Wo_b;
    float4v f = ((const float4v*)src)[j];
    dst[j] = bf16x4{(bf16)f.x, (bf16)f.y, (bf16)f.z, (bf16)f.w};
}

// ---------------------------------------------------------------------------
// C[M x N] = A[M x 512] @ W[N x 512]^T, bf16, K=512, BM=BN=128, BK=32.
// 256 thr = 4 waves, each owns a 64x64 quadrant (4x4 MFMA 16x16x32).
// 1-D launch; block -> (mt, nt) via XCD swizzle: bid%8 = xcd, blocks sharing
// an A row-tile are consecutive slots on ONE xcd -> A fetched once per chip.
// MODE 0: bf16 row-major out (ld 512).  MODE 1: KV — nt<4 K row-major into C0
// (ld 512), nt>=4 V transposed into C1 as Vt[b][d][lat].  MODE 2: fp32+bias.
template <int MODE>
__global__ __launch_bounds__(256) void gemm_bt(const bf16* __restrict__ A,
                                               const bf16* __restrict__ W,
                                               void* __restrict__ C0,
                                               void* __restrict__ C1,
                                               const float* __restrict__ bias,
                                               int nT, int mPerXcd) {
    __shared__ alignas(16) bf16 Asl[128 * 32];
    __shared__ alignas(16) bf16 Bsl[128 * 32];

    const int bid = blockIdx.x;
    const int xcd = bid & 7;
    const int s   = bid >> 3;
    const int mt  = xcd * mPerXcd + s / nT;
    const int nt  = s % nT;
    const int m0  = mt * 128;
    const int n0  = nt * 128;

    const int tid  = threadIdx.x;
    const int wave = tid >> 6;
    const int lane = tid & 63;
    const int mi   = lane & 15;
    const int quad = lane >> 4;
    const int qrow = (wave >> 1) * 64;
    const int qcol = (wave & 1) * 64;

    // staging: lane -> row wave*16 + r*64 + lane/4, col (lane&3)*8
    const int srow = wave * 16 + (lane >> 2);
    const int scol = (lane & 3) * 8;

    float4v acc[4][4] = {};

    for (int kt = 0; kt < 16; ++kt) {
        const int k0 = kt * 32;
#pragma unroll
        for (int r = 0; r < 2; ++r) {
            gl2lds16(A + (size_t)(m0 + srow + r * 64) * 512 + k0 + scol,
                     &Asl[wave * 512 + r * 2048]);
            gl2lds16(W + (size_t)(n0 + srow + r * 64) * 512 + k0 + scol,
                     &Bsl[wave * 512 + r * 2048]);
        }
        __syncthreads();

        bf16x8 af[4], bfr[4];
#pragma unroll
        for (int i = 0; i < 4; ++i)
            af[i] = *(const bf16x8*)&Asl[(qrow + i * 16 + mi) * 32 + quad * 8];
#pragma unroll
        for (int j = 0; j < 4; ++j)
            bfr[j] = *(const bf16x8*)&Bsl[(qcol + j * 16 + mi) * 32 + quad * 8];
#pragma unroll
        for (int i = 0; i < 4; ++i)
#pragma unroll
            for (int j = 0; j < 4; ++j)
                acc[i][j] = MFMA16(af[i], bfr[j], acc[i][j]);
        __syncthreads();
    }

    // epilogue: D[row = quad*4 + r][col = mi] per 16x16 tile
    if (MODE == 1 && nt >= 4) {
        // V half -> Vt[b][dd][lat], m-tile == one batch (BM = n_lat = 128)
        const size_t b = (size_t)mt;
#pragma unroll
        for (int i = 0; i < 4; ++i) {
            const int lat0 = qrow + i * 16 + quad * 4;
#pragma unroll
            for (int j = 0; j < 4; ++j) {
                const int dd = (n0 - 512) + qcol + j * 16 + mi;
                bf16x4 o = {(bf16)acc[i][j][0], (bf16)acc[i][j][1],
                            (bf16)acc[i][j][2], (bf16)acc[i][j][3]};
                *(bf16x4*)((bf16*)C1 + (b * 512 + dd) * 128 + lat0) = o;
            }
        }
        return;
    }
#pragma unroll
    for (int i = 0; i < 4; ++i) {
#pragma unroll
        for (int j = 0; j < 4; ++j) {
            const int row = m0 + qrow + i * 16 + quad * 4;
            const int col = n0 + qcol + j * 16 + mi;
#pragma unroll
            for (int r = 0; r < 4; ++r) {
                float v = acc[i][j][r];
                if (MODE == 2)
                    ((float*)C0)[(size_t)(row + r) * 512 + col] = v + bias[col];
                else
                    ((bf16*)C0)[(size_t)(row + r) * 512 + col] = (bf16)v;
            }
        }
    }
}

// ---------------------------------------------------------------------------
// Attention: 4 waves/block, wave w handles bh = blockIdx.x*4 + w.
// K row-major (131072, 512); Vt transposed (1024, 512, 128): all MFMA operands
// are contiguous 16B loads. Mask-aware: only ntiles = (b%128)/16+1 tiles live.
__global__ __launch_bounds__(256) void attn_kernel(const bf16* __restrict__ Q,
                                                   const bf16* __restrict__ K,
                                                   const bf16* __restrict__ Vt,
                                                   bf16* __restrict__ O) {
    __shared__ alignas(16) bf16 Plds[4][16 * 136];   // per-wave P tile, padded

    const int w      = threadIdx.x >> 6;
    const int bh     = blockIdx.x * 4 + w;
    const int b      = bh >> 3;
    const int h      = bh & 7;
    const int rowb   = b & 127;                   // allowed latents: j <= rowb
    const int ntiles = (rowb >> 4) + 1;           // active 16-latent tiles
    const int nkt    = (ntiles + 1) >> 1;         // active 32-latent PV k-steps
    const int lane   = threadIdx.x & 63;
    const int mi     = lane & 15;
    const int quad   = lane >> 4;

    // Q fragments: A[m=tok=mi][k=quad*8+j]
    const bf16* qbase = Q + (size_t)(b * 16 + mi) * 512 + h * 64 + quad * 8;
    const bf16x8 aq0 = *(const bf16x8*)(qbase);
    const bf16x8 aq1 = *(const bf16x8*)(qbase + 32);

    // scores: B[k=dh][n=lat] from K rows (BT form)
    float4v sc[8];
    const bf16* kbase = K + (size_t)(b * 128 + mi) * 512 + h * 64 + quad * 8;
#pragma unroll
    for (int jt = 0; jt < 8; ++jt) {
        if (jt < ntiles) {
            const bf16* kb = kbase + (size_t)jt * 16 * 512;
            bf16x8 bk0 = *(const bf16x8*)(kb);
            bf16x8 bk1 = *(const bf16x8*)(kb + 32);
            float4v a = {};
            a = MFMA16(aq0, bk0, a);
            a = MFMA16(aq1, bk1, a);
            sc[jt] = a;
        }
    }

    // mask boundary tile + scale (col = jt*16 + mi)
#pragma unroll
    for (int jt = 0; jt < 8; ++jt) {
        if (jt < ntiles) {
            const bool masked = (jt * 16 + mi) > rowb;
#pragma unroll
            for (int r = 0; r < 4; ++r)
                sc[jt][r] = masked ? -1e30f : sc[jt][r] * 0.125f;
        }
    }

    // softmax per token row (row = quad*4+r), reduce across the 16 mi lanes
#pragma unroll
    for (int r = 0; r < 4; ++r) {
        float mx = sc[0][r];
#pragma unroll
        for (int jt = 1; jt < 8; ++jt)
            if (jt < ntiles) mx = fmaxf(mx, sc[jt][r]);
#pragma unroll
        for (int off = 1; off < 16; off <<= 1) mx = fmaxf(mx, __shfl_xor(mx, off, 64));
        float s = 0.f;
#pragma unroll
        for (int jt = 0; jt < 8; ++jt) {
            if (jt < ntiles) {
                float p = __expf(sc[jt][r] - mx);
                sc[jt][r] = p;
                s += p;
            }
        }
#pragma unroll
        for (int off = 1; off < 16; off <<= 1) s += __shfl_xor(s, off, 64);
        const float inv = 1.f / s;
#pragma unroll
        for (int jt = 0; jt < 8; ++jt) {
            if (jt < 2 * nkt) {
                float p = (jt < ntiles) ? sc[jt][r] * inv : 0.f;
                Plds[w][(quad * 4 + r) * 136 + jt * 16 + mi] = (bf16)p;
            }
        }
    }
    __syncthreads();

    // out = P @ V: A[m=tok][k=lat] from Plds; B[k=lat][n=dd] from Vt rows.
    float4v ao[4] = {};
    const bf16* vb0 = Vt + ((size_t)b * 512 + h * 64) * 128;
#pragma unroll
    for (int ks = 0; ks < 4; ++ks) {
        if (ks < nkt) {
            bf16x8 ap = *(const bf16x8*)&Plds[w][mi * 136 + ks * 32 + quad * 8];
#pragma unroll
            for (int jt = 0; jt < 4; ++jt) {
                bf16x8 bv = *(const bf16x8*)(vb0 + (size_t)(jt * 16 + mi) * 128
                                             + ks * 32 + quad * 8);
                ao[jt] = MFMA16(ap, bv, ao[jt]);
            }
        }
    }

    // write merged-head output (16384, 512) bf16
#pragma unroll
    for (int jt = 0; jt < 4; ++jt)
#pragma unroll
        for (int r = 0; r < 4; ++r)
            O[(size_t)(b * 16 + quad * 4 + r) * 512 + h * 64 + jt * 16 + mi] =
                (bf16)ao[jt][r];
}

// ---------------------------------------------------------------------------
extern "C" void kernel_launch(void* const* d_in, const int* in_sizes, int n_in,
                              void* d_out, int out_size, void* d_ws, size_t ws_size,
                              hipStream_t stream) {
    const float* x  = (const float*)d_in[0];   // (16384, 512)
    const float* l  = (const float*)d_in[1];   // (131072, 512)
    const float* Wq = (const float*)d_in[2];
    const float* Wk = (const float*)d_in[3];
    const float* Wv = (const float*)d_in[4];
    const float* Wo = (const float*)d_in[5];
    const float* bo = (const float*)d_in[6];
    // d_in[7] = num_heads (8), hard-coded.

    char* ws = (char*)d_ws;
    size_t off = 0;
    bf16* Wq_b  = (bf16*)(ws + off); off += (size_t)512 * 512 * 2;
    bf16* Wo_b  = (bf16*)(ws + off); off += (size_t)512 * 512 * 2;
    bf16* Wkv_b = (bf16*)(ws + off); off += (size_t)1024 * 512 * 2;   // [Wk;Wv]
    bf16* xb    = (bf16*)(ws + off); off += (size_t)16384 * 512 * 2;
    bf16* lb    = (bf16*)(ws + off); off += (size_t)131072 * 512 * 2;
    bf16* Qb    = (bf16*)(ws + off); off += (size_t)16384 * 512 * 2;
    bf16* Kb    = (bf16*)(ws + off); off += (size_t)131072 * 512 * 2;
    bf16* Vtb   = (bf16*)(ws + off); off += (size_t)1024 * 512 * 128 * 2;
    bf16* AOb   = (bf16*)(ws + off);

    cast_weights<<<1024, 256, 0, stream>>>(Wq, Wk, Wv, Wo, Wq_b, Wkv_b, Wo_b);
    cast_f32_bf16<<<2048, 256, 0, stream>>>(x, xb, 16384 * 512 / 4);
    cast_f32_bf16<<<8192, 256, 0, stream>>>(l, lb, 131072 * 512 / 4);

    // Q: 128 m-tiles, 4 n-tiles; KV: 1024 m-tiles, 8 n-tiles (XCD-swizzled 1-D)
    gemm_bt<0><<<512,  256, 0, stream>>>(xb, Wq_b,  Qb, nullptr, nullptr, 4, 16);
    gemm_bt<1><<<8192, 256, 0, stream>>>(lb, Wkv_b, Kb, Vtb,     nullptr, 8, 128);

    attn_kernel<<<2048, 256, 0, stream>>>(Qb, Kb, Vtb, AOb);

    gemm_bt<2><<<512, 256, 0, stream>>>(AOb, Wo_b, d_out, nullptr, bo, 4, 16);
}